// Round 1
// baseline (25.506 us; speedup 1.0000x reference)
//
#include <hip/hip_runtime.h>
#include <math.h>

#define Sd 52
#define SS (Sd*Sd)      // 2704
#define Cc 80
#define NCc 85
#define NCH 255
#define Bb 64
#define Mm 50
#define DIVc 8.0f

__device__ __constant__ float AW[9] = {10.f,16.f,33.f,30.f,62.f,59.f,116.f,156.f,373.f};
__device__ __constant__ float AH[9] = {13.f,30.f,23.f,61.f,45.f,119.f,90.f,198.f,326.f};

__global__ __launch_bounds__(256) void yolo_main(
    const float* __restrict__ x,     // (B, 255, 52, 52)
    const float* __restrict__ geo,   // (B, 50, 4)
    const int*   __restrict__ cls,   // (B, 50)
    float* __restrict__ partial)     // (B,)
{
    const int b   = blockIdx.x;
    const int tid = threadIdx.x;

    __shared__ unsigned char removed[3*SS];      // 8112 B bitmap over (now, s1, s2)
    __shared__ int   s_valid[Mm];
    __shared__ int   s_off[Mm];                  // flat index of channel-base element
    __shared__ int   s_cls[Mm];
    __shared__ float rf[256];
    __shared__ float rn[256];
    __shared__ int   rc[256];

    for (int i = tid; i < 3*SS; i += 256) removed[i] = 0;
    __syncthreads();

    float lsum = 0.f;

    // ---------------- Phase 1: per-box decode + coord losses ----------------
    if (tid < Mm) {
        const int m = tid;
        const float cx = geo[(b*Mm+m)*4+0];
        const float cy = geo[(b*Mm+m)*4+1];
        const float w  = geo[(b*Mm+m)*4+2];
        const float h  = geo[(b*Mm+m)*4+3];

        // anchor argmax with reference's quirky IoU:
        // A=(aw+1)(ah+1), Bv=(w+1)(h+1), CM=(min(aw,w)+1)*(min(ah,h)-1)
        const float Bv = (w+1.f)*(h+1.f);
        float best = -INFINITY; int idx = 0;
        #pragma unroll
        for (int i = 0; i < 9; ++i) {
            const float A  = (AW[i]+1.f)*(AH[i]+1.f);
            const float CM = (fminf(AW[i],w)+1.f)*(fminf(AH[i],h)-1.f);
            const float iou = CM/(A+Bv-CM);
            if (iou > best) { best = iou; idx = i; }   // first-max tie-break
        }
        const int valid = (idx <= 2) ? 1 : 0;
        const int now   = idx < 2 ? idx : 2;

        int ix = (int)(cx * (1.f/DIVc)); ix = ix < 0 ? 0 : (ix > Sd-1 ? Sd-1 : ix);
        int iy = (int)(cy * (1.f/DIVc)); iy = iy < 0 ? 0 : (iy > Sd-1 ? Sd-1 : iy);
        const float ax = (cx - (float)ix*DIVc) * (1.f/DIVc);
        const float ay = (cy - (float)iy*DIVc) * (1.f/DIVc);

        const int off = ((b*NCH + now*NCc)*Sd + ix)*Sd + iy;

        const float obj = x[off];
        const float v1  = x[off + 1*SS];
        const float v2  = x[off + 2*SS];
        const float v3  = x[off + 3*SS];
        const float v4  = x[off + 4*SS];

        const float rax = 1.f/(1.f+expf(-v1));
        const float ray = 1.f/(1.f+expf(-v2));
        const float rw  = AW[idx]*expf(v3);
        const float rh  = AH[idx]*expf(v4);

        // iou_t with the same quirky formula (note y1+1 inside max, no +1 on that factor)
        const float X1 = rax*DIVc - rw*0.5f, Y1 = ray*DIVc - rh*0.5f;
        const float X2 = rax*DIVc + rw*0.5f, Y2 = ray*DIVc + rh*0.5f;
        const float x1 = ax*DIVc  - w*0.5f,  y1 = ay*DIVc  - h*0.5f;
        const float x2 = ax*DIVc  + w*0.5f,  y2 = ay*DIVc  + h*0.5f;
        const float A2  = (rw+1.f)*(rh+1.f);
        const float CM2 = (fminf(X2,x2)-fmaxf(X1,x1)+1.f) *
                          (fminf(Y2,y2)-fmaxf(Y1,y1+1.f));
        const float iou_t = CM2/(A2+Bv-CM2);

        const float d0 = obj-iou_t, d1 = rax-ax, d2 = ray-ay, d3 = rw-w, d4 = rh-h;
        const float pb = 5.f*d0*d0 + d1*d1 + d2*d2 + d3*d3 + d4*d4;

        if (valid) {
            lsum += pb;
            removed[now*SS + ix*Sd + iy] = 1;
        }
        s_valid[m] = valid;
        s_off[m]   = off;
        s_cls[m]   = cls[b*Mm+m];
    }
    __syncthreads();

    // ---------------- Phase 2: BCE over (m, c) pairs ----------------
    for (int t = tid; t < Mm*Cc; t += 256) {
        const int m = t / Cc;
        const int c = t - m*Cc;
        if (s_valid[m]) {
            const float v = x[s_off[m] + (5+c)*SS];
            const float label = 1.f/(1.f+expf(-v));
            float term;
            if (s_cls[m] == c) term = fmaxf(logf(label),    -100.f);
            else               term = fmaxf(log1pf(-label), -100.f);
            lsum -= term * (1.f/(float)Cc);
        }
    }

    // ---------------- Phase 3: noobj channels {0,85,170} ----------------
    float num = 0.f; int cnt = 0;
    const float* xb = x + (size_t)b*NCH*SS;
    for (int t = tid; t < 3*SS; t += 256) {
        const int nw = t / SS;
        const int s  = t - nw*SS;
        const float xv = xb[nw*NCc*SS + s];
        if (!removed[t]) num += xv*xv; else cnt++;
    }

    // ---------------- block reduce {lsum, num, cnt} ----------------
    rf[tid] = lsum; rn[tid] = num; rc[tid] = cnt;
    __syncthreads();
    for (int sh = 128; sh > 0; sh >>= 1) {
        if (tid < sh) {
            rf[tid] += rf[tid+sh];
            rn[tid] += rn[tid+sh];
            rc[tid] += rc[tid+sh];
        }
        __syncthreads();
    }
    if (tid == 0) {
        partial[b] = rf[0] + 0.5f * rn[0] / (float)(3*SS - rc[0]);
    }
}

__global__ void yolo_finalize(const float* __restrict__ partial,
                              float* __restrict__ out)
{
    float v = partial[threadIdx.x];    // 64 lanes = 1 wave
    #pragma unroll
    for (int o = 32; o > 0; o >>= 1) v += __shfl_down(v, o);
    if (threadIdx.x == 0) out[0] = v;
}

extern "C" void kernel_launch(void* const* d_in, const int* in_sizes, int n_in,
                              void* d_out, int out_size, void* d_ws, size_t ws_size,
                              hipStream_t stream) {
    const float* x   = (const float*)d_in[0];
    const float* geo = (const float*)d_in[1];
    const int*   cls = (const int*)d_in[2];
    float* out     = (float*)d_out;
    float* partial = (float*)d_ws;     // 64 floats

    yolo_main<<<Bb, 256, 0, stream>>>(x, geo, cls, partial);
    yolo_finalize<<<1, 64, 0, stream>>>(partial, out);
}

// Round 2
// 20.413 us; speedup vs baseline: 1.2495x; 1.2495x over previous
//
#include <hip/hip_runtime.h>
#include <math.h>

#define Sd 52
#define SS (Sd*Sd)      // 2704
#define Cc 80
#define NCc 85
#define NCH 255
#define Bb 64
#define Mm 50
#define DIVc 8.0f
#define KB 8                    // blocks per batch
#define BCE_TOT (Mm*Cc)         // 4000
#define BCE_SH  (BCE_TOT/KB)    // 500
#define NO_TOT  (3*SS)          // 8112
#define NO_SH   (NO_TOT/KB)     // 1014

__device__ __constant__ float AW[9] = {10.f,16.f,33.f,30.f,62.f,59.f,116.f,156.f,373.f};
__device__ __constant__ float AH[9] = {13.f,30.f,23.f,61.f,45.f,119.f,90.f,198.f,326.f};

__global__ __launch_bounds__(256) void yolo_main(
    const float* __restrict__ x,     // (B, 255, 52, 52)
    const float* __restrict__ geo,   // (B, 50, 4)
    const int*   __restrict__ cls,   // (B, 50)
    float* __restrict__ out)         // (1,) pre-zeroed by memsetAsync
{
    const int blk = blockIdx.x;
    const int b   = blk >> 3;        // blk / KB
    const int k   = blk & (KB-1);
    const int tid = threadIdx.x;

    __shared__ unsigned char removed[NO_TOT];    // 8112 B bitmap over (now, s1, s2)
    __shared__ int   s_valid[Mm];
    __shared__ int   s_off[Mm];
    __shared__ int   s_cls[Mm];
    __shared__ float rf[256];
    __shared__ float rn[256];
    __shared__ int   rc[256];

    unsigned int* rem32 = (unsigned int*)removed;
    for (int i = tid; i < NO_TOT/4; i += 256) rem32[i] = 0u;
    __syncthreads();

    float lsum = 0.f;

    // -------- Phase 1 (redundant in all KB blocks): decode + coord loss --------
    if (tid < Mm) {
        const int m = tid;
        const float cx = geo[(b*Mm+m)*4+0];
        const float cy = geo[(b*Mm+m)*4+1];
        const float w  = geo[(b*Mm+m)*4+2];
        const float h  = geo[(b*Mm+m)*4+3];

        // reference's quirky anchor IoU:
        // A=(aw+1)(ah+1), Bv=(w+1)(h+1), CM=(min(aw,w)+1)*(min(ah,h)-1)
        const float Bv = (w+1.f)*(h+1.f);
        float best = -INFINITY; int idx = 0;
        #pragma unroll
        for (int i = 0; i < 9; ++i) {
            const float A  = (AW[i]+1.f)*(AH[i]+1.f);
            const float CM = (fminf(AW[i],w)+1.f)*(fminf(AH[i],h)-1.f);
            const float iou = CM/(A+Bv-CM);
            if (iou > best) { best = iou; idx = i; }   // first-max tie-break
        }
        const int valid = (idx <= 2) ? 1 : 0;
        const int now   = idx < 2 ? idx : 2;

        int ix = (int)(cx * (1.f/DIVc)); ix = ix < 0 ? 0 : (ix > Sd-1 ? Sd-1 : ix);
        int iy = (int)(cy * (1.f/DIVc)); iy = iy < 0 ? 0 : (iy > Sd-1 ? Sd-1 : iy);
        const float ax = (cx - (float)ix*DIVc) * (1.f/DIVc);
        const float ay = (cy - (float)iy*DIVc) * (1.f/DIVc);

        const int off = ((b*NCH + now*NCc)*Sd + ix)*Sd + iy;

        if (valid) removed[now*SS + ix*Sd + iy] = 1;
        s_valid[m] = valid;
        s_off[m]   = off;
        s_cls[m]   = cls[b*Mm+m];

        if (k == 0) {   // coord loss counted once per batch
            const float obj = x[off];
            const float v1  = x[off + 1*SS];
            const float v2  = x[off + 2*SS];
            const float v3  = x[off + 3*SS];
            const float v4  = x[off + 4*SS];

            const float rax = 1.f/(1.f+expf(-v1));
            const float ray = 1.f/(1.f+expf(-v2));
            const float rw  = AW[idx]*expf(v3);
            const float rh  = AH[idx]*expf(v4);

            // iou_t with the reference's quirky formula (y1+1 inside max)
            const float X1 = rax*DIVc - rw*0.5f, Y1 = ray*DIVc - rh*0.5f;
            const float X2 = rax*DIVc + rw*0.5f, Y2 = ray*DIVc + rh*0.5f;
            const float x1 = ax*DIVc  - w*0.5f,  y1 = ay*DIVc  - h*0.5f;
            const float x2 = ax*DIVc  + w*0.5f,  y2 = ay*DIVc  + h*0.5f;
            const float A2  = (rw+1.f)*(rh+1.f);
            const float CM2 = (fminf(X2,x2)-fmaxf(X1,x1)+1.f) *
                              (fminf(Y2,y2)-fmaxf(Y1,y1+1.f));
            const float iou_t = CM2/(A2+Bv-CM2);

            const float d0 = obj-iou_t, d1 = rax-ax, d2 = ray-ay, d3 = rw-w, d4 = rh-h;
            const float pb = 5.f*d0*d0 + d1*d1 + d2*d2 + d3*d3 + d4*d4;
            if (valid) lsum += pb;
        }
    }
    __syncthreads();

    // -------- Phase 2: BCE share [k*500, (k+1)*500) of (m,c) pairs --------
    for (int t = k*BCE_SH + tid; t < (k+1)*BCE_SH; t += 256) {
        const int m = t / Cc;
        const int c = t - m*Cc;
        if (s_valid[m]) {
            const float v = x[s_off[m] + (5+c)*SS];
            const float label = 1.f/(1.f+expf(-v));
            float term;
            if (s_cls[m] == c) term = fmaxf(logf(label),    -100.f);
            else               term = fmaxf(log1pf(-label), -100.f);
            lsum -= term * (1.f/(float)Cc);
        }
    }

    // -------- Phase 3a: noobj num over share [k*1014, (k+1)*1014) --------
    float num = 0.f;
    const float* xb = x + (size_t)b*NCH*SS;
    for (int t = k*NO_SH + tid; t < (k+1)*NO_SH; t += 256) {
        const int nw = t / SS;
        const int s  = t - nw*SS;
        const float xv = xb[nw*NCc*SS + s];           // issue load unconditionally
        if (!removed[t]) num += xv*xv;
    }

    // -------- Phase 3b: cnt over FULL bitmap (bytes are 0/1) --------
    int cnt = 0;
    for (int i = tid; i < NO_TOT/4; i += 256) {
        const unsigned int wd = rem32[i];
        cnt += (int)((wd * 0x01010101u) >> 24);       // sum of 4 bytes
    }

    // -------- block reduce {lsum, num, cnt} --------
    rf[tid] = lsum; rn[tid] = num; rc[tid] = cnt;
    __syncthreads();
    for (int sh = 128; sh > 0; sh >>= 1) {
        if (tid < sh) {
            rf[tid] += rf[tid+sh];
            rn[tid] += rn[tid+sh];
            rc[tid] += rc[tid+sh];
        }
        __syncthreads();
    }
    if (tid == 0) {
        atomicAdd(out, rf[0] + 0.5f * rn[0] / (float)(NO_TOT - rc[0]));
    }
}

extern "C" void kernel_launch(void* const* d_in, const int* in_sizes, int n_in,
                              void* d_out, int out_size, void* d_ws, size_t ws_size,
                              hipStream_t stream) {
    const float* x   = (const float*)d_in[0];
    const float* geo = (const float*)d_in[1];
    const int*   cls = (const int*)d_in[2];
    float* out = (float*)d_out;

    hipMemsetAsync(out, 0, sizeof(float), stream);
    yolo_main<<<Bb*KB, 256, 0, stream>>>(x, geo, cls, out);
}